// Round 4
// baseline (133.220 us; speedup 1.0000x reference)
//
#include <hip/hip_runtime.h>
#include <math.h>

#define BB 2
#define TT 512
#define UU 48
#define DD 512
#define HH 1024
#define KK 128

typedef _Float16 f16x8 __attribute__((ext_vector_type(8)));
typedef __fp16 fp16x2_t __attribute__((ext_vector_type(2)));
typedef float floatx4 __attribute__((ext_vector_type(4)));

// tanh from pre-scaled input z = 2*log2(e)*x (stored f16 by mid):
// tanh(x) = 1 - 2/(2^z + 1). 2 trans + ~5 VALU per 2 elems, +-inf safe.
__device__ __forceinline__ f16x8 tanh8z(f16x8 z) {
    f16x8 o;
#pragma unroll
    for (int i = 0; i < 8; i += 2) {
        float e0 = __builtin_amdgcn_exp2f((float)z[i]);
        float e1 = __builtin_amdgcn_exp2f((float)z[i + 1]);
        float r0 = __builtin_amdgcn_rcpf(e0 + 1.0f);
        float r1 = __builtin_amdgcn_rcpf(e1 + 1.0f);
        fp16x2_t p = __builtin_amdgcn_cvt_pkrtz(fmaf(-2.0f, r0, 1.0f),
                                                fmaf(-2.0f, r1, 1.0f));
        o[i] = (_Float16)p[0];
        o[i + 1] = (_Float16)p[1];
    }
    return o;
}

// ---------------- mid v6: single-stage LDS-resident tiles ------------------
// Same geometry/regions as v5 (32x64 tile, 640 blocks) but: stage FULL
// A-tile (32x512 f16) + W-tile (64x512 f16) in one shot (48 float4/thread,
// one latency exposure), ONE barrier, then 16 LDS->MFMA k-steps with no
// further barriers. 99 KB LDS -> 1 block/CU; 2.5 block-rounds.
__global__ __launch_bounds__(256) void mid_kernel6(
    const float* __restrict__ img, const float* __restrict__ labf,
    const float* __restrict__ W1, const float* __restrict__ W2,
    const float* __restrict__ conv_w,
    const float* __restrict__ b1, const float* __restrict__ conv_b,
    const float* __restrict__ masks,
    _Float16* __restrict__ imgHf, _Float16* __restrict__ labHf,
    _Float16* __restrict__ W2s, float* __restrict__ seg_out) {
    int bid = blockIdx.x, tid = threadIdx.x;
    if (bid >= 624) {  // W2 swizzle: W2s[(h>>3)*1024 + k*8 + (h&7)] = W2[k][h]
        int base = (bid - 624) * 256 + tid;
#pragma unroll
        for (int i = 0; i < 32; ++i) {
            int o = base + i * 4096;
            int hg = o >> 10, kk2 = (o >> 3) & 127, hl = o & 7;
            W2s[o] = (_Float16)W2[(size_t)kk2 * HH + hg * 8 + hl];
        }
        return;
    }
    __shared__ __align__(16) _Float16 a_s[32][520];  // 32.5 KB (pad: +8)
    __shared__ __align__(16) _Float16 w_s[32768];    // 64 KB: [64 kg][64 n][8]
    const float* Arow;
    const float* Wbase;
    int r0, n0b, wstride, region;
    if (bid < 512) {
        region = 0; Arow = img; Wbase = W1 + 512; wstride = 2 * DD;
        int xcd = bid & 7, j = bid >> 3;
        r0 = (j & 31) * 32; n0b = (xcd * 2 + (j >> 5)) * 64;
    } else if (bid < 560) {
        region = 1; Arow = labf; Wbase = W1; wstride = 2 * DD;
        int i = bid - 512; r0 = (i % 3) * 32; n0b = (i / 3) * 64;
    } else {
        region = 2; Arow = img; Wbase = conv_w; wstride = DD;
        int i = bid - 560; r0 = (i >> 1) * 32; n0b = (i & 1) * 64;
    }
    int lane = tid & 63, wv = tid >> 6;
    int m0 = (wv & 1) * 16, n0w = (wv >> 1) * 32;
    int q = lane >> 4, r = lane & 15;
    int arow = tid >> 3, acol = (tid & 7) * 64;  // A: 8 thr/row, 64 f32 each
    int wn = tid >> 2, wk0 = (tid & 3) * 16;     // W: 4 thr/row, 16 f32 x 8 c
    const float* ap = &Arow[(size_t)(r0 + arow) * DD + acol];
    const float* wp = &Wbase[(size_t)(n0b + wn) * wstride + wk0];
    // ---- stage: issue all 48 float4 loads (one latency exposure) ----
    float4 pa[16], pw[32];
#pragma unroll
    for (int j = 0; j < 16; ++j) pa[j] = *(const float4*)(ap + j * 4);
#pragma unroll
    for (int c = 0; c < 8; ++c)
#pragma unroll
        for (int j = 0; j < 4; ++j)
            pw[c * 4 + j] = *(const float4*)(wp + c * 64 + j * 4);
    // convert + LDS-write A (8x 16B per thread)
#pragma unroll
    for (int j = 0; j < 8; ++j) {
        f16x8 v;
        v[0] = (_Float16)pa[2 * j].x; v[1] = (_Float16)pa[2 * j].y;
        v[2] = (_Float16)pa[2 * j].z; v[3] = (_Float16)pa[2 * j].w;
        v[4] = (_Float16)pa[2 * j + 1].x; v[5] = (_Float16)pa[2 * j + 1].y;
        v[6] = (_Float16)pa[2 * j + 1].z; v[7] = (_Float16)pa[2 * j + 1].w;
        *(f16x8*)&a_s[arow][acol + j * 8] = v;
    }
    // convert + LDS-write W (16x 16B per thread)
#pragma unroll
    for (int c = 0; c < 8; ++c) {
        int kg = c * 8 + (tid & 3) * 2;
        f16x8 w0, w1;
        w0[0] = (_Float16)pw[c * 4 + 0].x; w0[1] = (_Float16)pw[c * 4 + 0].y;
        w0[2] = (_Float16)pw[c * 4 + 0].z; w0[3] = (_Float16)pw[c * 4 + 0].w;
        w0[4] = (_Float16)pw[c * 4 + 1].x; w0[5] = (_Float16)pw[c * 4 + 1].y;
        w0[6] = (_Float16)pw[c * 4 + 1].z; w0[7] = (_Float16)pw[c * 4 + 1].w;
        w1[0] = (_Float16)pw[c * 4 + 2].x; w1[1] = (_Float16)pw[c * 4 + 2].y;
        w1[2] = (_Float16)pw[c * 4 + 2].z; w1[3] = (_Float16)pw[c * 4 + 2].w;
        w1[4] = (_Float16)pw[c * 4 + 3].x; w1[5] = (_Float16)pw[c * 4 + 3].y;
        w1[6] = (_Float16)pw[c * 4 + 3].z; w1[7] = (_Float16)pw[c * 4 + 3].w;
        *(f16x8*)&w_s[((kg + 0) * 64 + wn) * 8] = w0;
        *(f16x8*)&w_s[((kg + 1) * 64 + wn) * 8] = w1;
    }
    __syncthreads();  // the ONLY barrier
    // ---- 16 k-steps, pure LDS->MFMA ----
    floatx4 acc[2] = {};
#pragma unroll
    for (int k = 0; k < 16; ++k) {
        f16x8 af = *(const f16x8*)&a_s[m0 + r][k * 32 + q * 8];
#pragma unroll
        for (int nt = 0; nt < 2; ++nt) {
            f16x8 bf = *(const f16x8*)
                &w_s[((k * 4 + q) * 64 + n0w + nt * 16 + r) * 8];
            acc[nt] = __builtin_amdgcn_mfma_f32_16x16x32_f16(
                af, bf, acc[nt], 0, 0, 0);
        }
    }
    const float SC = 2.8853900817779268f;  // 2*log2(e): pre-scale for tanh8z
    if (region == 0) {
#pragma unroll
        for (int nt = 0; nt < 2; ++nt) {
            int n = n0b + n0w + nt * 16 + r;
#pragma unroll
            for (int rr = 0; rr < 4; ++rr)
                imgHf[(size_t)(r0 + m0 + 4 * q + rr) * HH + n] =
                    (_Float16)(acc[nt][rr] * SC);
        }
    } else if (region == 1) {
#pragma unroll
        for (int nt = 0; nt < 2; ++nt) {
            int n = n0b + n0w + nt * 16 + r;
            float bv = b1[n];
#pragma unroll
            for (int rr = 0; rr < 4; ++rr)
                labHf[(size_t)(r0 + m0 + 4 * q + rr) * HH + n] =
                    (_Float16)((acc[nt][rr] + bv) * SC);
        }
    } else {
#pragma unroll
        for (int nt = 0; nt < 2; ++nt) {
            int k = n0b + n0w + nt * 16 + r;
            float bv = conv_b[k];
#pragma unroll
            for (int rr = 0; rr < 4; ++rr) {
                int row = r0 + m0 + 4 * q + rr;
                int b = row >> 9, t = row & 511;
                seg_out[((size_t)b * KK + k) * TT + t] =
                    (acc[nt][rr] + bv) * masks[row];
            }
        }
    }
}

// ---------------- joint v9: UNCHANGED (controlled round) -------------------
__global__ __launch_bounds__(384, 2) void joint_kernel9(
    const _Float16* __restrict__ imgHf,  // [B*T][H], pre-scaled 2log2e
    const _Float16* __restrict__ labHf,  // [B*U][H], (.+b1) pre-scaled
    const _Float16* __restrict__ W2s,    // swizzled [(h>>3)][k][h&7]
    const float* __restrict__ b2,
    float* __restrict__ out) {           // [B*U*T][K]
    __shared__ __align__(16) _Float16 w_s[2][32768];  // 2 x 64 KB
    int tid = threadIdx.x, bid = blockIdx.x;
    int lane = tid & 63, wv = tid >> 6;
    int ql = lane >> 4, r = lane & 15;
    int g0 = bid * 192 + wv * 32;        // wave's first flat (b,u,t) row
    int gr0 = g0 + r, gr1 = g0 + 16 + r; // A-frag rows for m-tile 0/1
    int bu0 = gr0 >> 9, t0 = gr0 & 511;
    int bu1 = gr1 >> 9, t1 = gr1 & 511;
    const _Float16* ir0 = imgHf + (size_t)(((bu0 >= UU) ? TT : 0) + t0) * HH;
    const _Float16* ir1 = imgHf + (size_t)(((bu1 >= UU) ? TT : 0) + t1) * HH;
    const _Float16* lr0 = labHf + (size_t)bu0 * HH;
    const _Float16* lr1 = labHf + (size_t)bu1 * HH;
    int c0 = ql * 8, c1 = 32 + ql * 8;
    floatx4 acc0[8] = {}, acc1[8] = {};
    // stage quarter 0 -> buf0: 4096 f16x8 units over 384 threads (10..11 ea)
#pragma unroll
    for (int k2 = 0; k2 < 10; ++k2)
        *(f16x8*)&w_s[0][(tid + k2 * 384) * 8] =
            *(const f16x8*)&W2s[(tid + k2 * 384) * 8];
    if (tid < 256)
        *(f16x8*)&w_s[0][(tid + 3840) * 8] =
            *(const f16x8*)&W2s[(tid + 3840) * 8];
    // A chunk 0 -> regs
    f16x8 i0A = *(const f16x8*)&ir0[c0], i0B = *(const f16x8*)&ir0[c1];
    f16x8 i1A = *(const f16x8*)&ir1[c0], i1B = *(const f16x8*)&ir1[c1];
    f16x8 l0A = *(const f16x8*)&lr0[c0], l0B = *(const f16x8*)&lr0[c1];
    f16x8 l1A = *(const f16x8*)&lr1[c0], l1B = *(const f16x8*)&lr1[c1];
    __syncthreads();
    int buf = 0;
    for (int qq = 0; qq < 4; ++qq) {
        // register-prefetch next quarter's W2 (drains under this quarter's
        // 4 chunks of tanh+MFMA; written to other buffer just before barrier)
        f16x8 wr[11];
        if (qq < 3) {
            const _Float16* wsrc = W2s + (size_t)(qq + 1) * 32768;
#pragma unroll
            for (int k2 = 0; k2 < 10; ++k2)
                wr[k2] = *(const f16x8*)&wsrc[(tid + k2 * 384) * 8];
            if (tid < 256) wr[10] = *(const f16x8*)&wsrc[(tid + 3840) * 8];
        }
        const _Float16* wb = w_s[buf];
#pragma unroll
        for (int c = 0; c < 4; ++c) {
            int cc = qq * 4 + c;
            f16x8 ni0A, ni0B, ni1A, ni1B, nl0A, nl0B, nl1A, nl1B;
            if (cc < 15) {  // prefetch next 64-h chunk's A rows
                int cb = (cc + 1) * 64;
                ni0A = *(const f16x8*)&ir0[cb + c0];
                ni0B = *(const f16x8*)&ir0[cb + c1];
                ni1A = *(const f16x8*)&ir1[cb + c0];
                ni1B = *(const f16x8*)&ir1[cb + c1];
                nl0A = *(const f16x8*)&lr0[cb + c0];
                nl0B = *(const f16x8*)&lr0[cb + c1];
                nl1A = *(const f16x8*)&lr1[cb + c0];
                nl1B = *(const f16x8*)&lr1[cb + c1];
            }
            f16x8 a0A = tanh8z(i0A + l0A);
            f16x8 a1A = tanh8z(i1A + l1A);
#pragma unroll
            for (int nt = 0; nt < 8; ++nt) {  // bf feeds BOTH m-tiles
                f16x8 bf = *(const f16x8*)
                    &wb[c * 8192 + (ql * 128 + nt * 16 + r) * 8];
                acc0[nt] = __builtin_amdgcn_mfma_f32_16x16x32_f16(
                    a0A, bf, acc0[nt], 0, 0, 0);
                acc1[nt] = __builtin_amdgcn_mfma_f32_16x16x32_f16(
                    a1A, bf, acc1[nt], 0, 0, 0);
            }
            f16x8 a0B = tanh8z(i0B + l0B);
            f16x8 a1B = tanh8z(i1B + l1B);
#pragma unroll
            for (int nt = 0; nt < 8; ++nt) {
                f16x8 bf = *(const f16x8*)
                    &wb[c * 8192 + ((4 + ql) * 128 + nt * 16 + r) * 8];
                acc0[nt] = __builtin_amdgcn_mfma_f32_16x16x32_f16(
                    a0B, bf, acc0[nt], 0, 0, 0);
                acc1[nt] = __builtin_amdgcn_mfma_f32_16x16x32_f16(
                    a1B, bf, acc1[nt], 0, 0, 0);
            }
            if (cc < 15) {
                i0A = ni0A; i0B = ni0B; i1A = ni1A; i1B = ni1B;
                l0A = nl0A; l0B = nl0B; l1A = nl1A; l1B = nl1B;
            }
        }
        if (qq < 3) {  // commit next quarter into other buffer, ONE barrier
            _Float16* wd = w_s[buf ^ 1];
#pragma unroll
            for (int k2 = 0; k2 < 10; ++k2)
                *(f16x8*)&wd[(tid + k2 * 384) * 8] = wr[k2];
            if (tid < 256) *(f16x8*)&wd[(tid + 3840) * 8] = wr[10];
            __syncthreads();
            buf ^= 1;
        }
    }
    // epilogue: +b2, in-register log-softmax per 16-lane group's 128 cols
    float b2v[8];
#pragma unroll
    for (int nt = 0; nt < 8; ++nt) b2v[nt] = b2[nt * 16 + r];
#pragma unroll
    for (int mt = 0; mt < 2; ++mt) {
        float* obase = out + (size_t)(g0 + mt * 16 + 4 * ql) * KK;
#pragma unroll
        for (int rr = 0; rr < 4; ++rr) {
            float v[8];
            float mx = -INFINITY;
#pragma unroll
            for (int nt = 0; nt < 8; ++nt) {
                v[nt] = (mt ? acc1[nt][rr] : acc0[nt][rr]) + b2v[nt];
                mx = fmaxf(mx, v[nt]);
            }
            mx = fmaxf(mx, __shfl_xor(mx, 1, 16));
            mx = fmaxf(mx, __shfl_xor(mx, 2, 16));
            mx = fmaxf(mx, __shfl_xor(mx, 4, 16));
            mx = fmaxf(mx, __shfl_xor(mx, 8, 16));
            float s = 0.f;
#pragma unroll
            for (int nt = 0; nt < 8; ++nt) s += __expf(v[nt] - mx);
            s += __shfl_xor(s, 1, 16);
            s += __shfl_xor(s, 2, 16);
            s += __shfl_xor(s, 4, 16);
            s += __shfl_xor(s, 8, 16);
            float lse = mx + __logf(s);
#pragma unroll
            for (int nt = 0; nt < 8; ++nt)
                obase[(size_t)rr * KK + nt * 16 + r] = v[nt] - lse;
        }
    }
}

extern "C" void kernel_launch(void* const* d_in, const int* in_sizes, int n_in,
                              void* d_out, int out_size, void* d_ws, size_t ws_size,
                              hipStream_t stream) {
    const float* img    = (const float*)d_in[0];
    const float* labf   = (const float*)d_in[1];
    const float* masks  = (const float*)d_in[2];
    const float* W1     = (const float*)d_in[3];
    const float* b1     = (const float*)d_in[4];
    const float* W2     = (const float*)d_in[5];
    const float* b2     = (const float*)d_in[6];
    const float* conv_w = (const float*)d_in[7];
    const float* conv_b = (const float*)d_in[8];
    float* out = (float*)d_out;

    _Float16* base  = (_Float16*)d_ws;
    _Float16* imgHf = base;                    // [1024][1024]
    _Float16* labHf = imgHf + 1024 * 1024;     // [96][1024]
    _Float16* W2s   = labHf + 96 * 1024;       // [H/8][K][8] = 131072

    mid_kernel6<<<640, 256, 0, stream>>>(img, labf, W1, W2, conv_w,
                                         b1, conv_b, masks,
                                         imgHf, labHf, W2s, out);
    joint_kernel9<<<256, 384, 0, stream>>>(imgHf, labHf, W2s, b2,
                                           out + (size_t)BB * KK * TT);
}

// Round 5
// 123.720 us; speedup vs baseline: 1.0768x; 1.0768x over previous
//
#include <hip/hip_runtime.h>
#include <math.h>

#define BB 2
#define TT 512
#define UU 48
#define DD 512
#define HH 1024
#define KK 128

typedef _Float16 f16x8 __attribute__((ext_vector_type(8)));
typedef __fp16 fp16x2_t __attribute__((ext_vector_type(2)));
typedef float floatx4 __attribute__((ext_vector_type(4)));
typedef __attribute__((address_space(3))) _Float16 lds_f16;
typedef __attribute__((address_space(1))) const void g_cvoid;
typedef __attribute__((address_space(3))) void l_void;

// tanh from pre-scaled input z = 2*log2(e)*x (stored f16 by mid):
// tanh(x) = 1 - 2/(2^z + 1). 2 trans + ~5 VALU per 2 elems, +-inf safe.
__device__ __forceinline__ f16x8 tanh8z(f16x8 z) {
    f16x8 o;
#pragma unroll
    for (int i = 0; i < 8; i += 2) {
        float e0 = __builtin_amdgcn_exp2f((float)z[i]);
        float e1 = __builtin_amdgcn_exp2f((float)z[i + 1]);
        float r0 = __builtin_amdgcn_rcpf(e0 + 1.0f);
        float r1 = __builtin_amdgcn_rcpf(e1 + 1.0f);
        fp16x2_t p = __builtin_amdgcn_cvt_pkrtz(fmaf(-2.0f, r0, 1.0f),
                                                fmaf(-2.0f, r1, 1.0f));
        o[i] = (_Float16)p[0];
        o[i + 1] = (_Float16)p[1];
    }
    return o;
}

// ---------------- mid v5: reverted (v6 regressed) --------------------------
__global__ __launch_bounds__(256) void mid_kernel5(
    const float* __restrict__ img, const float* __restrict__ labf,
    const float* __restrict__ W1, const float* __restrict__ W2,
    const float* __restrict__ conv_w,
    const float* __restrict__ b1, const float* __restrict__ conv_b,
    const float* __restrict__ masks,
    _Float16* __restrict__ imgHf, _Float16* __restrict__ labHf,
    _Float16* __restrict__ W2s, float* __restrict__ seg_out) {
    int bid = blockIdx.x, tid = threadIdx.x;
    if (bid >= 624) {  // W2 swizzle: W2s[(h>>3)*1024 + k*8 + (h&7)] = W2[k][h]
        int base = (bid - 624) * 256 + tid;
#pragma unroll
        for (int i = 0; i < 32; ++i) {
            int o = base + i * 4096;
            int hg = o >> 10, kk2 = (o >> 3) & 127, hl = o & 7;
            W2s[o] = (_Float16)W2[(size_t)kk2 * HH + hg * 8 + hl];
        }
        return;
    }
    __shared__ __align__(16) _Float16 a_s[32][72];
    __shared__ __align__(16) _Float16 w_s[4096];  // [8 kgroups][64 n][8]
    const float* Arow;
    const float* Wbase;
    int r0, n0b, wstride, region;
    if (bid < 512) {
        region = 0; Arow = img; Wbase = W1 + 512; wstride = 2 * DD;
        int xcd = bid & 7, j = bid >> 3;
        r0 = (j & 31) * 32; n0b = (xcd * 2 + (j >> 5)) * 64;
    } else if (bid < 560) {
        region = 1; Arow = labf; Wbase = W1; wstride = 2 * DD;
        int i = bid - 512; r0 = (i % 3) * 32; n0b = (i / 3) * 64;
    } else {
        region = 2; Arow = img; Wbase = conv_w; wstride = DD;
        int i = bid - 560; r0 = (i >> 1) * 32; n0b = (i & 1) * 64;
    }
    int lane = tid & 63, wv = tid >> 6;
    int m0 = (wv & 1) * 16, n0w = (wv >> 1) * 32;
    int q = lane >> 4, r = lane & 15;
    int arow = tid >> 3, acol = (tid & 7) * 8;
    int wn = tid >> 2, wk0 = (tid & 3) * 16;  // 4 threads per W row, 16 k each
    const float* aptr = &Arow[(size_t)(r0 + arow) * DD + acol];
    const float* wptr = &Wbase[(size_t)(n0b + wn) * wstride + wk0];
    floatx4 acc[2] = {};
    float4 pa0, pa1, pw[4];
    pa0 = *(const float4*)aptr;
    pa1 = *(const float4*)(aptr + 4);
#pragma unroll
    for (int i2 = 0; i2 < 4; ++i2) pw[i2] = *(const float4*)(wptr + i2 * 4);
    for (int c = 0; c < 8; ++c) {
        f16x8 av;
        av[0] = (_Float16)pa0.x; av[1] = (_Float16)pa0.y;
        av[2] = (_Float16)pa0.z; av[3] = (_Float16)pa0.w;
        av[4] = (_Float16)pa1.x; av[5] = (_Float16)pa1.y;
        av[6] = (_Float16)pa1.z; av[7] = (_Float16)pa1.w;
        *(f16x8*)&a_s[arow][acol] = av;
        f16x8 w0, w1;
        w0[0] = (_Float16)pw[0].x; w0[1] = (_Float16)pw[0].y;
        w0[2] = (_Float16)pw[0].z; w0[3] = (_Float16)pw[0].w;
        w0[4] = (_Float16)pw[1].x; w0[5] = (_Float16)pw[1].y;
        w0[6] = (_Float16)pw[1].z; w0[7] = (_Float16)pw[1].w;
        w1[0] = (_Float16)pw[2].x; w1[1] = (_Float16)pw[2].y;
        w1[2] = (_Float16)pw[2].z; w1[3] = (_Float16)pw[2].w;
        w1[4] = (_Float16)pw[3].x; w1[5] = (_Float16)pw[3].y;
        w1[6] = (_Float16)pw[3].z; w1[7] = (_Float16)pw[3].w;
        int kg = wk0 >> 3;
        *(f16x8*)&w_s[((kg + 0) * 64 + wn) * 8] = w0;
        *(f16x8*)&w_s[((kg + 1) * 64 + wn) * 8] = w1;
        __syncthreads();
        if (c < 7) {
            int cb = (c + 1) * 64;
            pa0 = *(const float4*)(aptr + cb);
            pa1 = *(const float4*)(aptr + cb + 4);
#pragma unroll
            for (int i2 = 0; i2 < 4; ++i2)
                pw[i2] = *(const float4*)(wptr + cb + i2 * 4);
        }
#pragma unroll
        for (int kt = 0; kt < 2; ++kt) {
            f16x8 af = *(const f16x8*)&a_s[m0 + r][kt * 32 + q * 8];
#pragma unroll
            for (int nt = 0; nt < 2; ++nt) {
                f16x8 bf = *(const f16x8*)
                    &w_s[((kt * 4 + q) * 64 + n0w + nt * 16 + r) * 8];
                acc[nt] = __builtin_amdgcn_mfma_f32_16x16x32_f16(
                    af, bf, acc[nt], 0, 0, 0);
            }
        }
        __syncthreads();
    }
    const float SC = 2.8853900817779268f;  // 2*log2(e): pre-scale for tanh8z
    if (region == 0) {
#pragma unroll
        for (int nt = 0; nt < 2; ++nt) {
            int n = n0b + n0w + nt * 16 + r;
#pragma unroll
            for (int rr = 0; rr < 4; ++rr)
                imgHf[(size_t)(r0 + m0 + 4 * q + rr) * HH + n] =
                    (_Float16)(acc[nt][rr] * SC);
        }
    } else if (region == 1) {
#pragma unroll
        for (int nt = 0; nt < 2; ++nt) {
            int n = n0b + n0w + nt * 16 + r;
            float bv = b1[n];
#pragma unroll
            for (int rr = 0; rr < 4; ++rr)
                labHf[(size_t)(r0 + m0 + 4 * q + rr) * HH + n] =
                    (_Float16)((acc[nt][rr] + bv) * SC);
        }
    } else {
#pragma unroll
        for (int nt = 0; nt < 2; ++nt) {
            int k = n0b + n0w + nt * 16 + r;
            float bv = conv_b[k];
#pragma unroll
            for (int rr = 0; rr < 4; ++rr) {
                int row = r0 + m0 + 4 * q + rr;
                int b = row >> 9, t = row & 511;
                seg_out[((size_t)b * KK + k) * TT + t] =
                    (acc[nt][rr] + bv) * masks[row];
            }
        }
    }
}

// ---------------- joint v10: async DMA W2 + per-quarter A regs -------------
// 256 blocks x 384 thr (6 waves x 32 rows). W2 quarters (64 KB) arrive via
// global_load_lds DMA (waves 0-3, 16 ops each), double-buffered; counted
// s_waitcnt vmcnt(32) + raw s_barrier -> next quarter's DMA stays in flight
// across the whole quarter (T3/T4). A operands: 32 f16x8 regs per quarter,
// loaded at quarter end, compiler-waited at next quarter top. 4 barriers.
__global__ __launch_bounds__(384, 2) void joint_kernel10(
    const _Float16* __restrict__ imgHf,  // [B*T][H], pre-scaled 2log2e
    const _Float16* __restrict__ labHf,  // [B*U][H], (.+b1) pre-scaled
    const _Float16* __restrict__ W2s,    // swizzled [(h>>3)][k][h&7]
    const float* __restrict__ b2,
    float* __restrict__ out) {           // [B*U*T][K]
    __shared__ __align__(16) _Float16 w_s[2][32768];  // 2 x 64 KB
    int tid = threadIdx.x, bid = blockIdx.x;
    int lane = tid & 63, wv = tid >> 6;
    int ql = lane >> 4, r = lane & 15;
    int g0 = bid * 192 + wv * 32;        // wave's first flat (b,u,t) row
    int gr0 = g0 + r, gr1 = g0 + 16 + r; // A-frag rows for m-tile 0/1
    int bu0 = gr0 >> 9, t0 = gr0 & 511;
    int bu1 = gr1 >> 9, t1 = gr1 & 511;
    const _Float16* ir0 = imgHf + (size_t)(((bu0 >= UU) ? TT : 0) + t0) * HH;
    const _Float16* ir1 = imgHf + (size_t)(((bu1 >= UU) ? TT : 0) + t1) * HH;
    const _Float16* lr0 = labHf + (size_t)bu0 * HH;
    const _Float16* lr1 = labHf + (size_t)bu1 * HH;
    int c0 = ql * 8, c1 = 32 + ql * 8;
    floatx4 acc0[8] = {}, acc1[8] = {};
    // A register set for one quarter: [chunk][mtile][frag] = 32 f16x8
    f16x8 Ai[4][2][2], Al[4][2][2];

    // ---- prologue: DMA quarter 0 -> buf0; A quarter 0 -> regs; drain ----
    if (wv < 4) {
        const _Float16* gs = W2s + (size_t)wv * 16 * 512 + lane * 8;
        lds_f16* ls = (lds_f16*)&w_s[0][(size_t)wv * 16 * 512];
#pragma unroll
        for (int i = 0; i < 16; ++i)
            __builtin_amdgcn_global_load_lds((g_cvoid*)(gs + i * 512),
                                             (l_void*)(ls + i * 512), 16, 0, 0);
    }
#pragma unroll
    for (int c = 0; c < 4; ++c) {
        int cb = c * 64;
        Ai[c][0][0] = *(const f16x8*)&ir0[cb + c0];
        Ai[c][0][1] = *(const f16x8*)&ir0[cb + c1];
        Ai[c][1][0] = *(const f16x8*)&ir1[cb + c0];
        Ai[c][1][1] = *(const f16x8*)&ir1[cb + c1];
        Al[c][0][0] = *(const f16x8*)&lr0[cb + c0];
        Al[c][0][1] = *(const f16x8*)&lr0[cb + c1];
        Al[c][1][0] = *(const f16x8*)&lr1[cb + c0];
        Al[c][1][1] = *(const f16x8*)&lr1[cb + c1];
    }
    asm volatile("s_waitcnt vmcnt(0)" ::: "memory");
    __builtin_amdgcn_s_barrier();
    asm volatile("" ::: "memory");

#pragma unroll
    for (int qn = 0; qn < 4; ++qn) {
        const _Float16* wb = w_s[qn & 1];
        // issue next quarter's DMA into the other buffer (safe: all waves
        // passed the previous barrier, so nobody still reads it)
        if (qn < 3 && wv < 4) {
            const _Float16* gs = W2s + (size_t)(qn + 1) * 32768 +
                                 (size_t)wv * 16 * 512 + lane * 8;
            lds_f16* ls = (lds_f16*)&w_s[(qn + 1) & 1][(size_t)wv * 16 * 512];
#pragma unroll
            for (int i = 0; i < 16; ++i)
                __builtin_amdgcn_global_load_lds(
                    (g_cvoid*)(gs + i * 512), (l_void*)(ls + i * 512), 16, 0, 0);
        }
        // ---- 4 chunks of tanh + MFMA, pure reg/LDS ----
#pragma unroll
        for (int c = 0; c < 4; ++c) {
            f16x8 a0A = tanh8z(Ai[c][0][0] + Al[c][0][0]);
            f16x8 a1A = tanh8z(Ai[c][1][0] + Al[c][1][0]);
#pragma unroll
            for (int nt = 0; nt < 8; ++nt) {  // bf feeds BOTH m-tiles
                f16x8 bf = *(const f16x8*)
                    &wb[c * 8192 + (ql * 128 + nt * 16 + r) * 8];
                acc0[nt] = __builtin_amdgcn_mfma_f32_16x16x32_f16(
                    a0A, bf, acc0[nt], 0, 0, 0);
                acc1[nt] = __builtin_amdgcn_mfma_f32_16x16x32_f16(
                    a1A, bf, acc1[nt], 0, 0, 0);
            }
            f16x8 a0B = tanh8z(Ai[c][0][1] + Al[c][0][1]);
            f16x8 a1B = tanh8z(Ai[c][1][1] + Al[c][1][1]);
#pragma unroll
            for (int nt = 0; nt < 8; ++nt) {
                f16x8 bf = *(const f16x8*)
                    &wb[c * 8192 + ((4 + ql) * 128 + nt * 16 + r) * 8];
                acc0[nt] = __builtin_amdgcn_mfma_f32_16x16x32_f16(
                    a0B, bf, acc0[nt], 0, 0, 0);
                acc1[nt] = __builtin_amdgcn_mfma_f32_16x16x32_f16(
                    a1B, bf, acc1[nt], 0, 0, 0);
            }
        }
        if (qn < 3) {
            // reload A regs for next quarter (done being read above); the
            // compiler inserts its own counted vmcnt before first use next
            // quarter. These 32 loads stay in flight across the barrier.
#pragma unroll
            for (int c = 0; c < 4; ++c) {
                int cb = (qn + 1) * 256 + c * 64;
                Ai[c][0][0] = *(const f16x8*)&ir0[cb + c0];
                Ai[c][0][1] = *(const f16x8*)&ir0[cb + c1];
                Ai[c][1][0] = *(const f16x8*)&ir1[cb + c0];
                Ai[c][1][1] = *(const f16x8*)&ir1[cb + c1];
                Al[c][0][0] = *(const f16x8*)&lr0[cb + c0];
                Al[c][0][1] = *(const f16x8*)&lr0[cb + c1];
                Al[c][1][0] = *(const f16x8*)&lr1[cb + c0];
                Al[c][1][1] = *(const f16x8*)&lr1[cb + c1];
            }
            // counted wait: 48 outstanding (16 DMA older + 32 A newer);
            // vmcnt(32) completes the DMA for next quarter, keeps A in flight
            if (wv < 4) asm volatile("s_waitcnt vmcnt(32)" ::: "memory");
            __builtin_amdgcn_s_barrier();
            asm volatile("" ::: "memory");
        }
    }
    // epilogue: +b2, in-register log-softmax per 16-lane group's 128 cols
    float b2v[8];
#pragma unroll
    for (int nt = 0; nt < 8; ++nt) b2v[nt] = b2[nt * 16 + r];
#pragma unroll
    for (int mt = 0; mt < 2; ++mt) {
        float* obase = out + (size_t)(g0 + mt * 16 + 4 * ql) * KK;
#pragma unroll
        for (int rr = 0; rr < 4; ++rr) {
            float v[8];
            float mx = -INFINITY;
#pragma unroll
            for (int nt = 0; nt < 8; ++nt) {
                v[nt] = (mt ? acc1[nt][rr] : acc0[nt][rr]) + b2v[nt];
                mx = fmaxf(mx, v[nt]);
            }
            mx = fmaxf(mx, __shfl_xor(mx, 1, 16));
            mx = fmaxf(mx, __shfl_xor(mx, 2, 16));
            mx = fmaxf(mx, __shfl_xor(mx, 4, 16));
            mx = fmaxf(mx, __shfl_xor(mx, 8, 16));
            float s = 0.f;
#pragma unroll
            for (int nt = 0; nt < 8; ++nt) s += __expf(v[nt] - mx);
            s += __shfl_xor(s, 1, 16);
            s += __shfl_xor(s, 2, 16);
            s += __shfl_xor(s, 4, 16);
            s += __shfl_xor(s, 8, 16);
            float lse = mx + __logf(s);
#pragma unroll
            for (int nt = 0; nt < 8; ++nt)
                obase[(size_t)rr * KK + nt * 16 + r] = v[nt] - lse;
        }
    }
}

extern "C" void kernel_launch(void* const* d_in, const int* in_sizes, int n_in,
                              void* d_out, int out_size, void* d_ws, size_t ws_size,
                              hipStream_t stream) {
    const float* img    = (const float*)d_in[0];
    const float* labf   = (const float*)d_in[1];
    const float* masks  = (const float*)d_in[2];
    const float* W1     = (const float*)d_in[3];
    const float* b1     = (const float*)d_in[4];
    const float* W2     = (const float*)d_in[5];
    const float* b2     = (const float*)d_in[6];
    const float* conv_w = (const float*)d_in[7];
    const float* conv_b = (const float*)d_in[8];
    float* out = (float*)d_out;

    _Float16* base  = (_Float16*)d_ws;
    _Float16* imgHf = base;                    // [1024][1024]
    _Float16* labHf = imgHf + 1024 * 1024;     // [96][1024]
    _Float16* W2s   = labHf + 96 * 1024;       // [H/8][K][8] = 131072

    mid_kernel5<<<640, 256, 0, stream>>>(img, labf, W1, W2, conv_w,
                                         b1, conv_b, masks,
                                         imgHf, labHf, W2s, out);
    joint_kernel10<<<256, 384, 0, stream>>>(imgHf, labHf, W2s, b2,
                                            out + (size_t)BB * KK * TT);
}